// Round 1
// baseline (6293.535 us; speedup 1.0000x reference)
//
#include <hip/hip_runtime.h>
#include <hip/hip_bf16.h>

// Problem constants
#define B 128
#define T 256
#define E 300
#define HH 256     // hidden
#define O 5
#define NSTEP (2*T - 1)   // 511

// ---------------------------------------------------------------------------
// K0: transpose weights into workspace.
//   WcT[e][0:256]   = Wp[h][e]   (proj_x)
//   WcT[e][256:512] = Wg[h][e]   (gate)
//   WrT[k][j]       = Wr[j][k]   (j in [0,1280), k in [0,512))
// ---------------------------------------------------------------------------
__global__ __launch_bounds__(256) void k_transpose(
    const float* __restrict__ Wp, const float* __restrict__ Wg,
    const float* __restrict__ Wr, float* __restrict__ WcT,
    float* __restrict__ WrT) {
  int idx = blockIdx.x * 256 + threadIdx.x;
  if (idx < HH * E) {
    int h = idx / E;
    int e = idx % E;
    WcT[e * 512 + h]       = Wp[idx];
    WcT[e * 512 + 256 + h] = Wg[idx];
  }
  if (idx < 5 * HH * 2 * HH) {   // 1280*512
    int j = idx / 512;
    int k = idx % 512;
    WrT[k * 1280 + j] = Wr[idx];
  }
}

// ---------------------------------------------------------------------------
// K1: buffers[b][t][0:256] = h_buf, [256:512] = c_buf
//   c = emb @ Wp^T + bp ;  h = tanh(c) * sigmoid(emb @ Wg^T + bg)
// One block = one batch element x 16 tokens. 256 threads (thread = h index).
// ---------------------------------------------------------------------------
#define TT 16
__global__ __launch_bounds__(256) void k_buffers(
    const int* __restrict__ x_ids, const float* __restrict__ embed,
    const float* __restrict__ WcT, const float* __restrict__ bp,
    const float* __restrict__ bg, float* __restrict__ buffers) {
  __shared__ float lds[TT * E];
  const int b  = blockIdx.y;
  const int t0 = blockIdx.x * TT;
  const int tid = threadIdx.x;

  // gather 16 embedding rows into LDS (coalesced within each row)
  for (int i = tid; i < TT * E; i += 256) {
    int t = i / E;
    int e = i % E;
    int id = x_ids[b * T + t0 + t];
    lds[i] = embed[(size_t)id * E + e];
  }
  __syncthreads();

  const int h = tid;
  float accP[TT], accG[TT];
#pragma unroll
  for (int t = 0; t < TT; ++t) { accP[t] = bp[h]; accG[t] = bg[h]; }

  for (int e = 0; e < E; ++e) {
    float wp = WcT[e * 512 + h];
    float wg = WcT[e * 512 + 256 + h];
#pragma unroll
    for (int t = 0; t < TT; ++t) {
      float x = lds[t * E + e];
      accP[t] = fmaf(x, wp, accP[t]);
      accG[t] = fmaf(x, wg, accG[t]);
    }
  }

#pragma unroll
  for (int t = 0; t < TT; ++t) {
    float c  = accP[t];
    float hb = tanhf(c) * (1.f / (1.f + __expf(-accG[t])));
    size_t base = ((size_t)b * T + t0 + t) * 512;
    buffers[base + h]       = hb;
    buffers[base + 256 + h] = c;
  }
}

// ---------------------------------------------------------------------------
// K2: per-batch-element shift-reduce scan + final logits.
// One block per batch element, 256 threads (thread = hidden index).
// Stack kept in global ws: stack[b][depth][512] (h | c).
// ---------------------------------------------------------------------------
__global__ __launch_bounds__(256) void k_scan(
    const int* __restrict__ trans, const float* __restrict__ WrT,
    const float* __restrict__ br, const float* __restrict__ Wo,
    const float* __restrict__ bo, const float* __restrict__ buffers,
    float* __restrict__ stack, float* __restrict__ out) {
  const int b   = blockIdx.x;
  const int tid = threadIdx.x;
  __shared__ float xs[512];    // [hl | hr]
  __shared__ float red[256];

  const float* bufb = buffers + (size_t)b * T * 512;
  float* stk = stack + (size_t)b * T * 512;

  int sptr = 0, bptr = T;

  for (int s = 0; s < NSTEP; ++s) {
    int tr = trans[s * B + b];   // uniform across block
    if (tr == 0) {  // SHIFT: push buffers[bptr-1]
      const float* src = bufb + (size_t)(bptr - 1) * 512;
      float* dst = stk + (size_t)sptr * 512;
      dst[tid]       = src[tid];
      dst[256 + tid] = src[256 + tid];
      sptr++; bptr--;
      __syncthreads();
    } else {        // REDUCE
      const float* L = stk + (size_t)(sptr - 2) * 512;
      const float* R = stk + (size_t)(sptr - 1) * 512;
      xs[tid]       = L[tid];         // hl
      xs[256 + tid] = R[tid];         // hr
      float cl = L[256 + tid];
      float cr = R[256 + tid];
      __syncthreads();

      // proj[j] = sum_k WrT[k][j] * x[k] + br[j];  thread owns j, j+256, ..., j+1024
      float a0 = br[tid];
      float a1 = br[256 + tid];
      float a2 = br[512 + tid];
      float a3 = br[768 + tid];
      float a4 = br[1024 + tid];
      const float* w = WrT + tid;
      for (int k = 0; k < 512; ++k) {
        float xk = xs[k];
        const float* wr = w + k * 1280;
        a0 = fmaf(wr[0],    xk, a0);
        a1 = fmaf(wr[256],  xk, a1);
        a2 = fmaf(wr[512],  xk, a2);
        a3 = fmaf(wr[768],  xk, a3);
        a4 = fmaf(wr[1024], xk, a4);
      }
      float si  = 1.f / (1.f + __expf(-a0));
      float sfl = 1.f / (1.f + __expf(-a1));
      float sfr = 1.f / (1.f + __expf(-a2));
      float tg  = tanhf(a3);
      float so  = 1.f / (1.f + __expf(-a4));
      float cn  = si * tg + sfl * cl + sfr * cr;
      float hn  = so * tanhf(cn);

      __syncthreads();  // all reads of L/R complete before overwrite
      float* dst = stk + (size_t)(sptr - 2) * 512;
      dst[tid]       = hn;
      dst[256 + tid] = cn;
      sptr--;
      __syncthreads();
    }
  }

  // logits = final_h @ Wo^T + bo  (final_h = stack[sptr-1][0:256])
  float hj = stk[(size_t)(sptr - 1) * 512 + tid];
  for (int m = 0; m < O; ++m) {
    red[tid] = Wo[m * HH + tid] * hj;
    __syncthreads();
    for (int off = 128; off > 0; off >>= 1) {
      if (tid < off) red[tid] += red[tid + off];
      __syncthreads();
    }
    if (tid == 0) out[b * O + m] = red[0] + bo[m];
    __syncthreads();
  }
}

// ---------------------------------------------------------------------------
extern "C" void kernel_launch(void* const* d_in, const int* in_sizes, int n_in,
                              void* d_out, int out_size, void* d_ws, size_t ws_size,
                              hipStream_t stream) {
  const int*   x_ids = (const int*)d_in[0];
  const int*   trans = (const int*)d_in[1];
  const float* embed = (const float*)d_in[2];
  const float* Wp    = (const float*)d_in[3];
  const float* bp    = (const float*)d_in[4];
  const float* Wg    = (const float*)d_in[5];
  const float* bg    = (const float*)d_in[6];
  const float* Wr    = (const float*)d_in[7];
  const float* br    = (const float*)d_in[8];
  const float* Wo    = (const float*)d_in[9];
  const float* bo    = (const float*)d_in[10];
  float* out = (float*)d_out;

  float* ws      = (float*)d_ws;
  float* WcT     = ws;                          // 300*512      = 153600
  float* WrT     = WcT + 300 * 512;             // 512*1280     = 655360
  float* buffers = WrT + 512 * 1280;            // B*T*512      = 16777216
  float* stack   = buffers + (size_t)B * T * 512; // B*T*512    = 16777216

  k_transpose<<<(5 * HH * 2 * HH + 255) / 256, 256, 0, stream>>>(Wp, Wg, Wr, WcT, WrT);
  k_buffers<<<dim3(T / TT, B), 256, 0, stream>>>(x_ids, embed, WcT, bp, bg, buffers);
  k_scan<<<B, 256, 0, stream>>>(trans, WrT, br, Wo, bo, buffers, stack, out);
}